// Round 4
// baseline (290.057 us; speedup 1.0000x reference)
//
#include <hip/hip_runtime.h>
#include <cstdint>

namespace {

constexpr int kB   = 32;           // batches
constexpr int kN   = 131072;       // points per batch
constexpr int kC   = 6;            // channels
constexpr int TPB  = 256;          // threads per block
constexpr int NBLK = 1024;         // persistent grid: 4 blocks/CU on 256 CUs
constexpr int BLK_PER_BATCH  = NBLK / kB;            // 32
constexpr int ROWS_PER_BLK   = kN / BLK_PER_BATCH;   // 4096
constexpr int CHUNKS         = ROWS_PER_BLK / TPB;   // 16 chunks of 256 rows
constexpr int CHUNKS_PER_B   = kN / TPB;             // 512 chunks per batch
constexpr int WAVES = TPB / 64;    // 4

__device__ __forceinline__ int waveSum(int v) {
#pragma unroll
    for (int off = 32; off; off >>= 1) v += __shfl_xor(v, off, 64);
    return v;
}

__global__ __launch_bounds__(64) void k_init(uint32_t* __restrict__ ctr) {
    if (threadIdx.x == 0) *ctr = 0u;
}

__global__ __launch_bounds__(TPB, 4) void k_main(const float* __restrict__ pc,
                                                 const float* __restrict__ tt,
                                                 float* __restrict__ out,
                                                 uint32_t* __restrict__ counts,
                                                 uint32_t* __restrict__ ctr) {
    __shared__ uint64_t sMask[CHUNKS][WAVES];   // validity masks, live across barrier
    __shared__ int      sCnt[CHUNKS];           // per-chunk valid counts
    __shared__ int      sRed[2 * WAVES];        // reduction scratch
    __shared__ int      sPB[2];                 // [0]=blockBase [1]=batchTotal

    const int blk  = blockIdx.x;
    const int b    = blk >> 5;                  // batch
    const int sub  = blk & (BLK_PER_BATCH - 1); // block index within batch
    const int tid  = threadIdx.x;
    const int lane = tid & 63;
    const int wv   = tid >> 6;

    // Transform is uniform per block -> scalar loads
    const float* T = tt + b * 16;
    const float T0 = T[0], T1 = T[1], T2 = T[2],  T3  = T[3];
    const float T4 = T[4], T5 = T[5], T6 = T[6],  T7  = T[7];
    const float T8 = T[8], T9 = T[9], T10 = T[10], T11 = T[11];

    const size_t rowBase = (size_t)b * kN + (size_t)sub * ROWS_PER_BLK;

    // ---------------- Phase 1: read + classify ----------------
#pragma unroll
    for (int c = 0; c < CHUNKS; ++c) {
        const float2* row = (const float2*)(pc + (rowBase + (size_t)(c * TPB + tid)) * kC);
        const float2 a0 = row[0], a1 = row[1], a2 = row[2];
        const float x = a0.x, y = a0.y, z = a1.x;
        const float ns = (a1.y + a2.x) + a2.y;
        const float px = x * T0 + y * T4 + z * T8  + T3;
        const float py = x * T1 + y * T5 + z * T9  + T7;
        const float pz = x * T2 + y * T6 + z * T10 + T11;
        const bool valid = (px * px + py * py < 1.0f) && (pz < 1.0f) && (ns != 0.0f);
        const uint64_t m = __ballot(valid);
        if (lane == 0) sMask[c][wv] = m;
    }
    __syncthreads();

    if (tid < CHUNKS) {
        int s = 0;
#pragma unroll
        for (int w = 0; w < WAVES; ++w) s += __popcll(sMask[tid][w]);
        sCnt[tid] = s;
        __hip_atomic_store(&counts[b * CHUNKS_PER_B + sub * CHUNKS + tid], (uint32_t)s,
                           __ATOMIC_RELEASE, __HIP_MEMORY_SCOPE_AGENT);
    }
    __syncthreads();

    // ---------------- Device-wide barrier (all 1024 blocks resident) ----------------
    if (tid == 0) {
        __threadfence();
        __hip_atomic_fetch_add(ctr, 1u, __ATOMIC_ACQ_REL, __HIP_MEMORY_SCOPE_AGENT);
        while (__hip_atomic_load(ctr, __ATOMIC_ACQUIRE, __HIP_MEMORY_SCOPE_AGENT) < (uint32_t)NBLK)
            __builtin_amdgcn_s_sleep(4);
    }
    __syncthreads();
    __threadfence();   // acquire: invalidate stale local cache lines

    // ---------------- Phase 2: prefix + scatter ----------------
    // blockBase = sum of counts of chunks before my first chunk (within batch);
    // batchTotal = sum of all 512 chunk counts.
    const uint32_t* cb = counts + b * CHUNKS_PER_B;
    const int firstChunk = sub * CHUNKS;
    const int c0 = (int)__hip_atomic_load(&cb[tid],       __ATOMIC_RELAXED, __HIP_MEMORY_SCOPE_AGENT);
    const int c1 = (int)__hip_atomic_load(&cb[tid + 256], __ATOMIC_RELAXED, __HIP_MEMORY_SCOPE_AGENT);
    int myPref = (tid < firstChunk ? c0 : 0) + (tid + 256 < firstChunk ? c1 : 0);
    int myTot  = c0 + c1;
    const int pw = waveSum(myPref);
    const int tw = waveSum(myTot);
    if (lane == 0) { sRed[wv] = pw; sRed[WAVES + wv] = tw; }
    __syncthreads();
    if (tid == 0) {
        sPB[0] = (sRed[0] + sRed[1]) + (sRed[2] + sRed[3]);
        sPB[1] = (sRed[4] + sRed[5]) + (sRed[6] + sRed[7]);
    }
    __syncthreads();

    int run = sPB[0];              // valid rows before current chunk (uniform)
    const int total = sPB[1];
    const size_t outB = (size_t)b * kN;

#pragma unroll
    for (int c = 0; c < CHUNKS; ++c) {
        const uint64_t m = sMask[c][wv];
        const bool valid = (m >> lane) & 1ull;
        int waveBase = 0;
#pragma unroll
        for (int w = 0; w < WAVES - 1; ++w)
            if (w < wv) waveBase += __popcll(sMask[c][w]);
        const int before = __popcll(m & ((1ull << lane) - 1ull));
        const int vcnt = run + waveBase + before;      // valid strictly before n
        const int n = sub * ROWS_PER_BLK + c * TPB + tid;

        if (valid) {
            const float2* row = (const float2*)(pc + (outB + (size_t)n) * kC);
            const float2 a0 = row[0], a1 = row[1], a2 = row[2];   // LLC-hot re-read
            float2* o = (float2*)(out + (outB + (size_t)vcnt) * kC);
            o[0] = a0; o[1] = a1; o[2] = a2;
        } else {
            const int dst = total + (n - vcnt);        // total + invalid-rank
            float2* o = (float2*)(out + (outB + (size_t)dst) * kC);
            const float2 zz = make_float2(0.0f, 0.0f);
            o[0] = zz; o[1] = zz; o[2] = zz;
        }
        run += sCnt[c];
    }
}

} // namespace

extern "C" void kernel_launch(void* const* d_in, const int* in_sizes, int n_in,
                              void* d_out, int out_size, void* d_ws, size_t ws_size,
                              hipStream_t stream) {
    const float* pc = (const float*)d_in[0];   // (32, 131072, 6) f32
    const float* tt = (const float*)d_in[1];   // (32, 4, 4) f32
    float* out = (float*)d_out;                // (32, 131072, 6) f32

    // ws layout: [0] barrier counter | [64 ..) 16384 chunk counts
    uint32_t* ctr    = (uint32_t*)d_ws;
    uint32_t* counts = (uint32_t*)d_ws + 64;

    k_init<<<1, 64, 0, stream>>>(ctr);
    k_main<<<NBLK, TPB, 0, stream>>>(pc, tt, out, counts, ctr);
}

// Round 5
// 39.415 us; speedup vs baseline: 7.3591x; 7.3591x over previous
//
#include <hip/hip_runtime.h>
#include <cstdint>

namespace {

constexpr int kB   = 32;            // batches
constexpr int kN   = 131072;        // points per batch
constexpr int kC   = 6;             // channels
constexpr int TPB  = 256;           // threads per block
constexpr int ROWS_PER_BLK = 512;   // 2 rows per thread
constexpr int BPB  = kN / ROWS_PER_BLK;   // 256 blocks per batch
constexpr int NBLK = kB * BPB;            // 8192 blocks total
constexpr int WAVES = TPB / 64;           // 4

__device__ __forceinline__ int waveSum(int v) {
#pragma unroll
    for (int off = 32; off; off >>= 1) v += __shfl_xor(v, off, 64);
    return v;
}

// Pass 1: classify 512 rows/block. Reads are 3 consecutive float4 per thread
// (16 B/lane, every line touched once). Publishes per-wave validity masks
// (even/odd row interleave) + per-block valid count.
__global__ __launch_bounds__(TPB) void k_count(const float* __restrict__ pc,
                                               const float* __restrict__ tt,
                                               uint64_t* __restrict__ masks,
                                               int* __restrict__ blkCnt) {
    const int blk  = blockIdx.x;
    const int b    = blk >> 8;          // blk / BPB
    const int tid  = threadIdx.x;
    const int lane = tid & 63;
    const int wv   = tid >> 6;

    const float* T = tt + b * 16;       // 4x4 row-major (uniform -> scalar regs)
    const float T0 = T[0], T1 = T[1], T2 = T[2],  T3  = T[3];
    const float T4 = T[4], T5 = T[5], T6 = T[6],  T7  = T[7];
    const float T8 = T[8], T9 = T[9], T10 = T[10], T11 = T[11];

    // Block's 512 rows = 768 float4; thread t owns f4[3t..3t+2] = rows 2t,2t+1.
    const float4* f4 = (const float4*)pc + (size_t)blk * (ROWS_PER_BLK * kC / 4);
    const float4 q0 = f4[3 * tid];
    const float4 q1 = f4[3 * tid + 1];
    const float4 q2 = f4[3 * tid + 2];

    // even row: x,y,z,nx = q0 ; ny,nz = q1.x,q1.y
    const float ns0 = (q0.w + q1.x) + q1.y;
    const float px0 = q0.x * T0 + q0.y * T4 + q0.z * T8  + T3;
    const float py0 = q0.x * T1 + q0.y * T5 + q0.z * T9  + T7;
    const float pz0 = q0.x * T2 + q0.y * T6 + q0.z * T10 + T11;
    const bool v0 = (px0 * px0 + py0 * py0 < 1.0f) && (pz0 < 1.0f) && (ns0 != 0.0f);

    // odd row: x,y = q1.z,q1.w ; z,nx,ny,nz = q2
    const float ns1 = (q2.y + q2.z) + q2.w;
    const float px1 = q1.z * T0 + q1.w * T4 + q2.x * T8  + T3;
    const float py1 = q1.z * T1 + q1.w * T5 + q2.x * T9  + T7;
    const float pz1 = q1.z * T2 + q1.w * T6 + q2.x * T10 + T11;
    const bool v1 = (px1 * px1 + py1 * py1 < 1.0f) && (pz1 < 1.0f) && (ns1 != 0.0f);

    const uint64_t m0 = __ballot(v0);   // rows wv*128 + 2*lane
    const uint64_t m1 = __ballot(v1);   // rows wv*128 + 2*lane + 1

    __shared__ uint64_t sm[WAVES * 2];
    if (lane == 0) {
        sm[wv * 2]     = m0;
        sm[wv * 2 + 1] = m1;
        masks[(size_t)blk * 8 + wv * 2]     = m0;
        masks[(size_t)blk * 8 + wv * 2 + 1] = m1;
    }
    __syncthreads();
    if (wv == 0) {
        int v = (lane < 8) ? __popcll(sm[lane]) : 0;
        v = waveSum(v);
        if (lane == 0) blkCnt[blk] = v;
    }
}

// Pass 2: per-block prefix via 256-count reduction (L2-hot), gather-write the
// ~7% valid rows, and zero-fill a dense contiguous slice of the batch tail.
__global__ __launch_bounds__(TPB) void k_scatter(const float* __restrict__ pc,
                                                 const uint64_t* __restrict__ masks,
                                                 const int* __restrict__ blkCnt,
                                                 float* __restrict__ out) {
    const int blk  = blockIdx.x;
    const int b    = blk >> 8;
    const int sub  = blk & (BPB - 1);
    const int tid  = threadIdx.x;
    const int lane = tid & 63;
    const int wv   = tid >> 6;

    __shared__ uint64_t sm[8];
    __shared__ int sRed[2 * WAVES];

    if (tid < 8) sm[tid] = masks[(size_t)blk * 8 + tid];   // one cache line

    // prefix over blocks sub' < sub, and batch total (BPB == TPB == 256)
    const int c = blkCnt[b * BPB + tid];
    const int pw = waveSum((tid < sub) ? c : 0);
    const int tw = waveSum(c);
    if (lane == 0) { sRed[wv] = pw; sRed[WAVES + wv] = tw; }
    __syncthreads();
    const int blockBase = (sRed[0] + sRed[1]) + (sRed[2] + sRed[3]);
    const int total     = (sRed[4] + sRed[5]) + (sRed[6] + sRed[7]);

    const uint64_t m0 = sm[wv * 2], m1 = sm[wv * 2 + 1];
    int wb = 0;
#pragma unroll
    for (int w = 0; w < WAVES - 1; ++w)
        if (w < wv) wb += __popcll(sm[w * 2]) + __popcll(sm[w * 2 + 1]);

    const uint64_t low = (1ull << lane) - 1ull;
    const int beforeE = __popcll(m0 & low) + __popcll(m1 & low);
    const bool v0 = (m0 >> lane) & 1ull;
    const bool v1 = (m1 >> lane) & 1ull;

    const size_t batchF = (size_t)b * kN * kC;       // batch base in floats
    const int rowBlk = sub * ROWS_PER_BLK + wv * 128 + 2 * lane;
    const int vcnt0 = blockBase + wb + beforeE;      // rank of even row
    const int vcnt1 = vcnt0 + (v0 ? 1 : 0);          // rank of odd row

    if (v0) {
        const float2* r = (const float2*)(pc + batchF + (size_t)rowBlk * kC);
        float2* o = (float2*)(out + batchF + (size_t)vcnt0 * kC);
        o[0] = r[0]; o[1] = r[1]; o[2] = r[2];
    }
    if (v1) {
        const float2* r = (const float2*)(pc + batchF + (size_t)(rowBlk + 1) * kC);
        float2* o = (float2*)(out + batchF + (size_t)vcnt1 * kC);
        o[0] = r[0]; o[1] = r[1]; o[2] = r[2];
    }

    // Dense zero-fill: batch tail rows [total, kN) split across the 256 blocks.
    const int tail = kN - total;
    const int len  = (tail + BPB - 1) >> 8;
    const int r0 = total + sub * len;
    const int r1 = min(r0 + len, kN);
    if (r0 < r1) {
        float2* o2 = (float2*)(out + batchF);
        const float2 zz = make_float2(0.0f, 0.0f);
        const int e0 = r0 * 3, e1 = r1 * 3;          // row = 3 float2
        for (int i = e0 + tid; i < e1; i += TPB) o2[i] = zz;
    }
}

} // namespace

extern "C" void kernel_launch(void* const* d_in, const int* in_sizes, int n_in,
                              void* d_out, int out_size, void* d_ws, size_t ws_size,
                              hipStream_t stream) {
    const float* pc = (const float*)d_in[0];   // (32, 131072, 6) f32
    const float* tt = (const float*)d_in[1];   // (32, 4, 4) f32
    float* out = (float*)d_out;                // (32, 131072, 6) f32

    // ws layout: masks (NBLK*8 u64 = 512 KiB) | blkCnt (NBLK ints = 32 KiB)
    uint64_t* masks = (uint64_t*)d_ws;
    int* blkCnt     = (int*)((char*)d_ws + (size_t)NBLK * 8 * sizeof(uint64_t));

    k_count<<<NBLK, TPB, 0, stream>>>(pc, tt, masks, blkCnt);
    k_scatter<<<NBLK, TPB, 0, stream>>>(pc, masks, blkCnt, out);
}

// Round 6
// 38.945 us; speedup vs baseline: 7.4478x; 1.0121x over previous
//
#include <hip/hip_runtime.h>
#include <cstdint>

namespace {

constexpr int kB   = 32;            // batches
constexpr int kN   = 131072;        // points per batch
constexpr int kC   = 6;             // channels
constexpr int TPB  = 256;           // threads per block
constexpr int ROWS_PER_BLK = 512;   // 2 rows per thread
constexpr int BPB  = kN / ROWS_PER_BLK;   // 256 blocks per batch
constexpr int NBLK = kB * BPB;            // 8192 blocks total
constexpr int WAVES = TPB / 64;           // 4

__device__ __forceinline__ int waveSum(int v) {
#pragma unroll
    for (int off = 32; off; off >>= 1) v += __shfl_xor(v, off, 64);
    return v;
}

// Pass 1: classify 512 rows/block. Reads are 3 consecutive float4 per thread
// (16 B/lane, every line touched once). Publishes per-wave validity masks
// (even/odd row interleave) + per-block valid count.
__global__ __launch_bounds__(TPB) void k_count(const float* __restrict__ pc,
                                               const float* __restrict__ tt,
                                               uint64_t* __restrict__ masks,
                                               int* __restrict__ blkCnt) {
    const int blk  = blockIdx.x;
    const int b    = blk >> 8;          // blk / BPB
    const int tid  = threadIdx.x;
    const int lane = tid & 63;
    const int wv   = tid >> 6;

    const float* T = tt + b * 16;       // 4x4 row-major (uniform -> scalar regs)
    const float T0 = T[0], T1 = T[1], T2 = T[2],  T3  = T[3];
    const float T4 = T[4], T5 = T[5], T6 = T[6],  T7  = T[7];
    const float T8 = T[8], T9 = T[9], T10 = T[10], T11 = T[11];

    // Block's 512 rows = 768 float4; thread t owns f4[3t..3t+2] = rows 2t,2t+1.
    const float4* f4 = (const float4*)pc + (size_t)blk * (ROWS_PER_BLK * kC / 4);
    const float4 q0 = f4[3 * tid];
    const float4 q1 = f4[3 * tid + 1];
    const float4 q2 = f4[3 * tid + 2];

    // even row: x,y,z,nx = q0 ; ny,nz = q1.x,q1.y
    const float ns0 = (q0.w + q1.x) + q1.y;
    const float px0 = q0.x * T0 + q0.y * T4 + q0.z * T8  + T3;
    const float py0 = q0.x * T1 + q0.y * T5 + q0.z * T9  + T7;
    const float pz0 = q0.x * T2 + q0.y * T6 + q0.z * T10 + T11;
    const bool v0 = (px0 * px0 + py0 * py0 < 1.0f) && (pz0 < 1.0f) && (ns0 != 0.0f);

    // odd row: x,y = q1.z,q1.w ; z,nx,ny,nz = q2
    const float ns1 = (q2.y + q2.z) + q2.w;
    const float px1 = q1.z * T0 + q1.w * T4 + q2.x * T8  + T3;
    const float py1 = q1.z * T1 + q1.w * T5 + q2.x * T9  + T7;
    const float pz1 = q1.z * T2 + q1.w * T6 + q2.x * T10 + T11;
    const bool v1 = (px1 * px1 + py1 * py1 < 1.0f) && (pz1 < 1.0f) && (ns1 != 0.0f);

    const uint64_t m0 = __ballot(v0);   // rows wv*128 + 2*lane
    const uint64_t m1 = __ballot(v1);   // rows wv*128 + 2*lane + 1

    __shared__ uint64_t sm[WAVES * 2];
    if (lane == 0) {
        sm[wv * 2]     = m0;
        sm[wv * 2 + 1] = m1;
        masks[(size_t)blk * 8 + wv * 2]     = m0;
        masks[(size_t)blk * 8 + wv * 2 + 1] = m1;
    }
    __syncthreads();
    if (wv == 0) {
        int v = (lane < 8) ? __popcll(sm[lane]) : 0;
        v = waveSum(v);
        if (lane == 0) blkCnt[blk] = v;
    }
}

// Pass 2: per-block prefix via 256-count reduction (L2-hot), gather-write the
// ~7% valid rows (LLC-hot), zero-fill a dense per-block slice of the batch
// tail with float4 stores (one optional float2 head/tail for 24B-row parity).
__global__ __launch_bounds__(TPB) void k_scatter(const float* __restrict__ pc,
                                                 const uint64_t* __restrict__ masks,
                                                 const int* __restrict__ blkCnt,
                                                 float* __restrict__ out) {
    const int blk  = blockIdx.x;
    const int b    = blk >> 8;
    const int sub  = blk & (BPB - 1);
    const int tid  = threadIdx.x;
    const int lane = tid & 63;
    const int wv   = tid >> 6;

    __shared__ uint64_t sm[8];
    __shared__ int sRed[2 * WAVES];

    if (tid < 8) sm[tid] = masks[(size_t)blk * 8 + tid];   // one cache line

    // prefix over blocks sub' < sub, and batch total (BPB == TPB == 256)
    const int c = blkCnt[b * BPB + tid];
    const int pw = waveSum((tid < sub) ? c : 0);
    const int tw = waveSum(c);
    if (lane == 0) { sRed[wv] = pw; sRed[WAVES + wv] = tw; }
    __syncthreads();
    const int blockBase = (sRed[0] + sRed[1]) + (sRed[2] + sRed[3]);
    const int total     = (sRed[4] + sRed[5]) + (sRed[6] + sRed[7]);

    const uint64_t m0 = sm[wv * 2], m1 = sm[wv * 2 + 1];
    int wb = 0;
#pragma unroll
    for (int w = 0; w < WAVES - 1; ++w)
        if (w < wv) wb += __popcll(sm[w * 2]) + __popcll(sm[w * 2 + 1]);

    const uint64_t low = (1ull << lane) - 1ull;
    const int beforeE = __popcll(m0 & low) + __popcll(m1 & low);
    const bool v0 = (m0 >> lane) & 1ull;
    const bool v1 = (m1 >> lane) & 1ull;

    const size_t batchF = (size_t)b * kN * kC;       // batch base in floats
    const int rowBlk = sub * ROWS_PER_BLK + wv * 128 + 2 * lane;
    const int vcnt0 = blockBase + wb + beforeE;      // rank of even row
    const int vcnt1 = vcnt0 + (v0 ? 1 : 0);          // rank of odd row

    if (v0) {
        const float2* r = (const float2*)(pc + batchF + (size_t)rowBlk * kC);
        float2* o = (float2*)(out + batchF + (size_t)vcnt0 * kC);
        o[0] = r[0]; o[1] = r[1]; o[2] = r[2];
    }
    if (v1) {
        const float2* r = (const float2*)(pc + batchF + (size_t)(rowBlk + 1) * kC);
        float2* o = (float2*)(out + batchF + (size_t)vcnt1 * kC);
        o[0] = r[0]; o[1] = r[1]; o[2] = r[2];
    }

    // Dense zero-fill: batch tail rows [total, kN) split across the 256 blocks.
    // Row = 24 B, so (row*6) mod 4 is 0 or 2: float4 body + <=1 float2 head/tail.
    const int tail = kN - total;
    const int len  = (tail + BPB - 1) >> 8;          // rows per block
    const int r0 = total + sub * len;
    const int r1 = min(r0 + len, kN);
    if (r0 < r1) {
        float* base = out + batchF;                  // 16B-aligned
        const int f0 = r0 * 6, f1 = r1 * 6;
        if (tid == 0) {
            const float2 zz = make_float2(0.0f, 0.0f);
            if (f0 & 3) *(float2*)(base + f0) = zz;          // head (8B-aligned)
            if (f1 & 3) *(float2*)(base + (f1 & ~3)) = zz;   // tail
        }
        const int a4 = (f0 + 3) >> 2;                // first full float4
        const int b4 = f1 >> 2;                      // end float4
        float4* o4 = (float4*)base;
        const float4 z4 = make_float4(0.0f, 0.0f, 0.0f, 0.0f);
        for (int i = a4 + tid; i < b4; i += TPB) o4[i] = z4;
    }
}

} // namespace

extern "C" void kernel_launch(void* const* d_in, const int* in_sizes, int n_in,
                              void* d_out, int out_size, void* d_ws, size_t ws_size,
                              hipStream_t stream) {
    const float* pc = (const float*)d_in[0];   // (32, 131072, 6) f32
    const float* tt = (const float*)d_in[1];   // (32, 4, 4) f32
    float* out = (float*)d_out;                // (32, 131072, 6) f32

    // ws layout: masks (NBLK*8 u64 = 512 KiB) | blkCnt (NBLK ints = 32 KiB)
    uint64_t* masks = (uint64_t*)d_ws;
    int* blkCnt     = (int*)((char*)d_ws + (size_t)NBLK * 8 * sizeof(uint64_t));

    k_count<<<NBLK, TPB, 0, stream>>>(pc, tt, masks, blkCnt);
    k_scatter<<<NBLK, TPB, 0, stream>>>(pc, masks, blkCnt, out);
}

// Round 7
// 37.493 us; speedup vs baseline: 7.7364x; 1.0387x over previous
//
#include <hip/hip_runtime.h>
#include <cstdint>

namespace {

constexpr int kB   = 32;            // batches
constexpr int kN   = 131072;        // points per batch
constexpr int kC   = 6;             // channels
constexpr int TPB  = 256;           // threads per block
constexpr int ROWS_PER_BLK = 512;   // 2 rows per thread
constexpr int BPB  = kN / ROWS_PER_BLK;   // 256 blocks per batch
constexpr int NBLK = kB * BPB;            // 8192 blocks total
constexpr int WAVES = TPB / 64;           // 4
constexpr int F4_PER_BLK = ROWS_PER_BLK * kC / 4;  // 768 float4 per block

__device__ __forceinline__ int waveSum(int v) {
#pragma unroll
    for (int off = 32; off; off >>= 1) v += __shfl_xor(v, off, 64);
    return v;
}

// ---------------- FAST PATH (ws >= ~101 MB): stage compacted rows ----------------

// Pass 1: dense coalesced float4 loads -> LDS -> row reassembly -> classify ->
// write per-block compacted valid rows to ws + per-block count.
__global__ __launch_bounds__(TPB) void k_count_stage(const float* __restrict__ pc,
                                                     const float* __restrict__ tt,
                                                     float* __restrict__ staged,
                                                     int* __restrict__ blkCnt) {
    const int blk  = blockIdx.x;
    const int b    = blk >> 8;          // blk / BPB
    const int tid  = threadIdx.x;
    const int lane = tid & 63;
    const int wv   = tid >> 6;

    const float* T = tt + b * 16;       // uniform -> scalar regs
    const float T0 = T[0], T1 = T[1], T2 = T[2],  T3  = T[3];
    const float T4 = T[4], T5 = T[5], T6 = T[6],  T7  = T[7];
    const float T8 = T[8], T9 = T[9], T10 = T[10], T11 = T[11];

    // Dense, fully-coalesced global reads (lane i -> consecutive 16 B).
    const float4* f4 = (const float4*)pc + (size_t)blk * F4_PER_BLK;
    const float4 qa = f4[tid];
    const float4 qb = f4[tid + 256];
    const float4 qc = f4[tid + 512];

    __shared__ float4 sb[F4_PER_BLK];
    sb[tid] = qa; sb[tid + 256] = qb; sb[tid + 512] = qc;
    __syncthreads();

    // Rows 2*tid, 2*tid+1 = float2[6*tid .. 6*tid+5]
    const float2* s2 = (const float2*)sb;
    const float2 r0a = s2[6 * tid],     r0b = s2[6 * tid + 1], r0c = s2[6 * tid + 2];
    const float2 r1a = s2[6 * tid + 3], r1b = s2[6 * tid + 4], r1c = s2[6 * tid + 5];

    // even row: x,y = r0a ; z,nx = r0b ; ny,nz = r0c
    const float ns0 = (r0b.y + r0c.x) + r0c.y;
    const float px0 = r0a.x * T0 + r0a.y * T4 + r0b.x * T8  + T3;
    const float py0 = r0a.x * T1 + r0a.y * T5 + r0b.x * T9  + T7;
    const float pz0 = r0a.x * T2 + r0a.y * T6 + r0b.x * T10 + T11;
    const bool v0 = (px0 * px0 + py0 * py0 < 1.0f) && (pz0 < 1.0f) && (ns0 != 0.0f);

    // odd row: x,y = r1a ; z,nx = r1b ; ny,nz = r1c
    const float ns1 = (r1b.y + r1c.x) + r1c.y;
    const float px1 = r1a.x * T0 + r1a.y * T4 + r1b.x * T8  + T3;
    const float py1 = r1a.x * T1 + r1a.y * T5 + r1b.x * T9  + T7;
    const float pz1 = r1a.x * T2 + r1a.y * T6 + r1b.x * T10 + T11;
    const bool v1 = (px1 * px1 + py1 * py1 < 1.0f) && (pz1 < 1.0f) && (ns1 != 0.0f);

    const uint64_t m0 = __ballot(v0);   // rows wv*128 + 2*lane
    const uint64_t m1 = __ballot(v1);   // rows wv*128 + 2*lane + 1

    __shared__ uint64_t sm[WAVES * 2];
    if (lane == 0) { sm[wv * 2] = m0; sm[wv * 2 + 1] = m1; }
    __syncthreads();

    if (wv == 0) {
        int v = (lane < 8) ? __popcll(sm[lane]) : 0;
        v = waveSum(v);
        if (lane == 0) blkCnt[blk] = v;
    }

    // In-block stable compaction rank
    int wb = 0;
#pragma unroll
    for (int w = 0; w < WAVES - 1; ++w)
        if (w < wv) wb += __popcll(sm[w * 2]) + __popcll(sm[w * 2 + 1]);
    const uint64_t low = (1ull << lane) - 1ull;
    const int beforeE = __popcll(m0 & low) + __popcll(m1 & low);
    const int rk0 = wb + beforeE;
    const int rk1 = rk0 + (v0 ? 1 : 0);

    float2* st = (float2*)(staged + (size_t)blk * (ROWS_PER_BLK * kC));
    if (v0) { float2* o = st + rk0 * 3; o[0] = r0a; o[1] = r0b; o[2] = r0c; }
    if (v1) { float2* o = st + rk1 * 3; o[0] = r1a; o[1] = r1b; o[2] = r1c; }
}

// Pass 2: prefix via 256-count reduction, dense copy staged->out, zero-fill tail.
__global__ __launch_bounds__(TPB) void k_emit(const float* __restrict__ staged,
                                              const int* __restrict__ blkCnt,
                                              float* __restrict__ out) {
    const int blk  = blockIdx.x;
    const int b    = blk >> 8;
    const int sub  = blk & (BPB - 1);
    const int tid  = threadIdx.x;
    const int lane = tid & 63;
    const int wv   = tid >> 6;

    __shared__ int sRed[2 * WAVES];

    const int c = blkCnt[b * BPB + tid];
    const int pw = waveSum((tid < sub) ? c : 0);
    const int tw = waveSum(c);
    if (lane == 0) { sRed[wv] = pw; sRed[WAVES + wv] = tw; }
    __syncthreads();
    const int blockBase = (sRed[0] + sRed[1]) + (sRed[2] + sRed[3]);
    const int total     = (sRed[4] + sRed[5]) + (sRed[6] + sRed[7]);
    const int myCnt     = blkCnt[blk];

    const size_t batchF = (size_t)b * kN * kC;

    // Dense copy of this block's compacted valid rows (src 16B-al, dst 8B-al).
    const float2* src = (const float2*)(staged + (size_t)blk * (ROWS_PER_BLK * kC));
    float2* dst = (float2*)(out + batchF + (size_t)blockBase * kC);
    const int nf2 = myCnt * 3;
    for (int i = tid; i < nf2; i += TPB) dst[i] = src[i];

    // Dense zero-fill: batch tail rows [total, kN) split across 256 blocks.
    const int tail = kN - total;
    const int len  = (tail + BPB - 1) >> 8;
    const int r0 = total + sub * len;
    const int r1 = min(r0 + len, kN);
    if (r0 < r1) {
        float* base = out + batchF;                  // 16B-aligned
        const int f0 = r0 * 6, f1 = r1 * 6;
        if (tid == 0) {
            const float2 zz = make_float2(0.0f, 0.0f);
            if (f0 & 3) *(float2*)(base + f0) = zz;          // head (8B-aligned)
            if (f1 & 3) *(float2*)(base + (f1 & ~3)) = zz;   // tail
        }
        const int a4 = (f0 + 3) >> 2;
        const int b4 = f1 >> 2;
        float4* o4 = (float4*)base;
        const float4 z4 = make_float4(0.0f, 0.0f, 0.0f, 0.0f);
        for (int i = a4 + tid; i < b4; i += TPB) o4[i] = z4;
    }
}

// ---------------- FALLBACK PATH (small ws): R6 mask-based kernels ----------------

__global__ __launch_bounds__(TPB) void k_count(const float* __restrict__ pc,
                                               const float* __restrict__ tt,
                                               uint64_t* __restrict__ masks,
                                               int* __restrict__ blkCnt) {
    const int blk  = blockIdx.x;
    const int b    = blk >> 8;
    const int tid  = threadIdx.x;
    const int lane = tid & 63;
    const int wv   = tid >> 6;

    const float* T = tt + b * 16;
    const float T0 = T[0], T1 = T[1], T2 = T[2],  T3  = T[3];
    const float T4 = T[4], T5 = T[5], T6 = T[6],  T7  = T[7];
    const float T8 = T[8], T9 = T[9], T10 = T[10], T11 = T[11];

    const float4* f4 = (const float4*)pc + (size_t)blk * F4_PER_BLK;
    const float4 q0 = f4[3 * tid];
    const float4 q1 = f4[3 * tid + 1];
    const float4 q2 = f4[3 * tid + 2];

    const float ns0 = (q0.w + q1.x) + q1.y;
    const float px0 = q0.x * T0 + q0.y * T4 + q0.z * T8  + T3;
    const float py0 = q0.x * T1 + q0.y * T5 + q0.z * T9  + T7;
    const float pz0 = q0.x * T2 + q0.y * T6 + q0.z * T10 + T11;
    const bool v0 = (px0 * px0 + py0 * py0 < 1.0f) && (pz0 < 1.0f) && (ns0 != 0.0f);

    const float ns1 = (q2.y + q2.z) + q2.w;
    const float px1 = q1.z * T0 + q1.w * T4 + q2.x * T8  + T3;
    const float py1 = q1.z * T1 + q1.w * T5 + q2.x * T9  + T7;
    const float pz1 = q1.z * T2 + q1.w * T6 + q2.x * T10 + T11;
    const bool v1 = (px1 * px1 + py1 * py1 < 1.0f) && (pz1 < 1.0f) && (ns1 != 0.0f);

    const uint64_t m0 = __ballot(v0);
    const uint64_t m1 = __ballot(v1);

    __shared__ uint64_t sm[WAVES * 2];
    if (lane == 0) {
        sm[wv * 2]     = m0;
        sm[wv * 2 + 1] = m1;
        masks[(size_t)blk * 8 + wv * 2]     = m0;
        masks[(size_t)blk * 8 + wv * 2 + 1] = m1;
    }
    __syncthreads();
    if (wv == 0) {
        int v = (lane < 8) ? __popcll(sm[lane]) : 0;
        v = waveSum(v);
        if (lane == 0) blkCnt[blk] = v;
    }
}

__global__ __launch_bounds__(TPB) void k_scatter(const float* __restrict__ pc,
                                                 const uint64_t* __restrict__ masks,
                                                 const int* __restrict__ blkCnt,
                                                 float* __restrict__ out) {
    const int blk  = blockIdx.x;
    const int b    = blk >> 8;
    const int sub  = blk & (BPB - 1);
    const int tid  = threadIdx.x;
    const int lane = tid & 63;
    const int wv   = tid >> 6;

    __shared__ uint64_t sm[8];
    __shared__ int sRed[2 * WAVES];

    if (tid < 8) sm[tid] = masks[(size_t)blk * 8 + tid];

    const int c = blkCnt[b * BPB + tid];
    const int pw = waveSum((tid < sub) ? c : 0);
    const int tw = waveSum(c);
    if (lane == 0) { sRed[wv] = pw; sRed[WAVES + wv] = tw; }
    __syncthreads();
    const int blockBase = (sRed[0] + sRed[1]) + (sRed[2] + sRed[3]);
    const int total     = (sRed[4] + sRed[5]) + (sRed[6] + sRed[7]);

    const uint64_t m0 = sm[wv * 2], m1 = sm[wv * 2 + 1];
    int wb = 0;
#pragma unroll
    for (int w = 0; w < WAVES - 1; ++w)
        if (w < wv) wb += __popcll(sm[w * 2]) + __popcll(sm[w * 2 + 1]);

    const uint64_t low = (1ull << lane) - 1ull;
    const int beforeE = __popcll(m0 & low) + __popcll(m1 & low);
    const bool v0 = (m0 >> lane) & 1ull;
    const bool v1 = (m1 >> lane) & 1ull;

    const size_t batchF = (size_t)b * kN * kC;
    const int rowBlk = sub * ROWS_PER_BLK + wv * 128 + 2 * lane;
    const int vcnt0 = blockBase + wb + beforeE;
    const int vcnt1 = vcnt0 + (v0 ? 1 : 0);

    if (v0) {
        const float2* r = (const float2*)(pc + batchF + (size_t)rowBlk * kC);
        float2* o = (float2*)(out + batchF + (size_t)vcnt0 * kC);
        o[0] = r[0]; o[1] = r[1]; o[2] = r[2];
    }
    if (v1) {
        const float2* r = (const float2*)(pc + batchF + (size_t)(rowBlk + 1) * kC);
        float2* o = (float2*)(out + batchF + (size_t)vcnt1 * kC);
        o[0] = r[0]; o[1] = r[1]; o[2] = r[2];
    }

    const int tail = kN - total;
    const int len  = (tail + BPB - 1) >> 8;
    const int r0 = total + sub * len;
    const int r1 = min(r0 + len, kN);
    if (r0 < r1) {
        float* base = out + batchF;
        const int f0 = r0 * 6, f1 = r1 * 6;
        if (tid == 0) {
            const float2 zz = make_float2(0.0f, 0.0f);
            if (f0 & 3) *(float2*)(base + f0) = zz;
            if (f1 & 3) *(float2*)(base + (f1 & ~3)) = zz;
        }
        const int a4 = (f0 + 3) >> 2;
        const int b4 = f1 >> 2;
        float4* o4 = (float4*)base;
        const float4 z4 = make_float4(0.0f, 0.0f, 0.0f, 0.0f);
        for (int i = a4 + tid; i < b4; i += TPB) o4[i] = z4;
    }
}

} // namespace

extern "C" void kernel_launch(void* const* d_in, const int* in_sizes, int n_in,
                              void* d_out, int out_size, void* d_ws, size_t ws_size,
                              hipStream_t stream) {
    const float* pc = (const float*)d_in[0];   // (32, 131072, 6) f32
    const float* tt = (const float*)d_in[1];   // (32, 4, 4) f32
    float* out = (float*)d_out;                // (32, 131072, 6) f32

    const size_t stagedBytes = (size_t)NBLK * ROWS_PER_BLK * kC * sizeof(float); // 100.7 MB
    const size_t cntBytes    = (size_t)NBLK * sizeof(int);

    if (ws_size >= stagedBytes + cntBytes) {
        float* staged = (float*)d_ws;
        int* blkCnt   = (int*)((char*)d_ws + stagedBytes);
        k_count_stage<<<NBLK, TPB, 0, stream>>>(pc, tt, staged, blkCnt);
        k_emit<<<NBLK, TPB, 0, stream>>>(staged, blkCnt, out);
    } else {
        uint64_t* masks = (uint64_t*)d_ws;
        int* blkCnt     = (int*)((char*)d_ws + (size_t)NBLK * 8 * sizeof(uint64_t));
        k_count<<<NBLK, TPB, 0, stream>>>(pc, tt, masks, blkCnt);
        k_scatter<<<NBLK, TPB, 0, stream>>>(pc, masks, blkCnt, out);
    }
}